// Round 11
// baseline (128.658 us; speedup 1.0000x reference)
//
#include <hip/hip_runtime.h>
#include <hip/hip_bf16.h>
#include <math.h>

#define B 4
#define N 512
#define IN_DIM 128
#define OUT_DIM 128
#define HEADS 4
#define PER_HEAD 32
#define NT (N / 64)   // 8 j-tiles of 64
#define IT 2          // target nodes per block (attn)
#define LROWS 4       // rows per block (linear)

// R11 = green R9 + ONE delta (bisect discipline after R10's post-timing
// divergence): xl buffer dropped; attn phase 3 reads xlT4 (same values,
// different addresses). Everything else — 3 dispatches, u64 ballot-free
// mask, ws offsets (xl slot left unused) — byte-preserved from R9.

// ---------------------------------------------------------------------------
// Kernel 1: xl/xr = x@W+b (fp32 ws; xl only in transposed ch-group-of-4 form),
// plus axl/axr = att-dot rows for the factorized leaky score.
// ---------------------------------------------------------------------------
__global__ __launch_bounds__(128) void gat_linear(
    const float* __restrict__ x, const float* __restrict__ Wl,
    const float* __restrict__ bl, const float* __restrict__ Wr,
    const float* __restrict__ br, const float* __restrict__ att,
    float* __restrict__ xr, float* __restrict__ xlT,
    float* __restrict__ axl, float* __restrict__ axr) {
    const int r0  = blockIdx.x * LROWS;
    const int col = threadIdx.x;          // col = h*32 + c
    __shared__ float xs[LROWS][IN_DIM];
#pragma unroll
    for (int r = 0; r < LROWS; ++r)
        xs[r][col] = x[(r0 + r) * IN_DIM + col];
    __syncthreads();

    float accl[LROWS], accr[LROWS];
    {
        const float blv = bl[col];
        const float brv = br[col];
#pragma unroll
        for (int r = 0; r < LROWS; ++r) { accl[r] = blv; accr[r] = brv; }
    }
#pragma unroll 8
    for (int k = 0; k < IN_DIM; ++k) {
        const float wl = Wl[k * OUT_DIM + col];
        const float wr = Wr[k * OUT_DIM + col];
#pragma unroll
        for (int r = 0; r < LROWS; ++r) {
            accl[r] = fmaf(xs[r][k], wl, accl[r]);
            accr[r] = fmaf(xs[r][k], wr, accr[r]);
        }
    }
    const float attc = att[col];          // att[h*PER_HEAD + c] == att[col]
    const int h = col >> 5;
#pragma unroll
    for (int r = 0; r < LROWS; ++r) {
        const int row = r0 + r;
        const int b = row >> 9, n = row & (N - 1);
        xr[row * OUT_DIM + col] = accr[r];
        xlT[((b * 32 + (col >> 2)) * N + n) * 4 + (col & 3)] = accl[r];
        // att-dot over the 32-lane channel group (lanes [0,31]/[32,63] of wave)
        float pl = attc * accl[r];
        float pr = attc * accr[r];
#pragma unroll
        for (int d = 1; d < 32; d <<= 1) {
            pl += __shfl_xor(pl, d);
            pr += __shfl_xor(pr, d);
        }
        if ((col & 31) == 0) {
            axl[(b * HEADS + h) * N + n] = pl;
            axr[(b * HEADS + h) * N + n] = pr;
        }
    }
}

// ---------------------------------------------------------------------------
// Kernel 2: adjacency bitmask, transposed, diagonal forced. lane <-> i
// (coalesced adj rows); each lane assembles its own u64 over j. (R9 exact.)
// ---------------------------------------------------------------------------
__global__ __launch_bounds__(256) void gat_mask(
    const int* __restrict__ adj, unsigned long long* __restrict__ maskT) {
    const int b    = blockIdx.y;
    const int i    = blockIdx.x * 64 + (threadIdx.x & 63);
    const int wave = threadIdx.x >> 6;
    for (int t = wave; t < NT; t += 4) {
        unsigned long long m = 0ull;
#pragma unroll 8
        for (int jj = 0; jj < 64; ++jj) {
            const int j = t * 64 + jj;
            const int v = adj[((size_t)b * N + j) * N + i];
            m |= (unsigned long long)(v != 0) << jj;
        }
        if ((i >> 6) == t) m |= 1ull << (i & 63);   // self-loop
        maskT[(size_t)(b * N + i) * NT + t] = m;
    }
}

// ---------------------------------------------------------------------------
// Kernel 3: fused scores + segment-softmax + aggregation. 1 wave per block.
// e_ij = 0.6(axr_i+axl_j) + sum_c 0.4*att_c*|xr_i+xl_j|; phase 3 reads xlT4.
// ---------------------------------------------------------------------------
__global__ __launch_bounds__(64) void gat_attn(
    const float* __restrict__ xr, const float* __restrict__ xlT,
    const float* __restrict__ axl, const float* __restrict__ axr,
    const unsigned long long* __restrict__ maskT,
    const float* __restrict__ att, const float* __restrict__ bias,
    float* __restrict__ out) {
    const int lane = threadIdx.x;         // 0..63 (one wave)
    const int h    = blockIdx.y;          // head
    const int i0   = blockIdx.x * IT;
    const int b    = blockIdx.z;

    __shared__ float a_s[IT][N];          // 4 KB

    float att04[PER_HEAD];                // 0.4 * att
#pragma unroll
    for (int c = 0; c < PER_HEAD; ++c) att04[c] = 0.4f * att[h * PER_HEAD + c];
    float xrv[IT][PER_HEAD];
#pragma unroll
    for (int ii = 0; ii < IT; ++ii)
#pragma unroll
        for (int c = 0; c < PER_HEAD; ++c)
            xrv[ii][c] = xr[(b * N + i0 + ii) * OUT_DIM + h * PER_HEAD + c];
    float axr_i[IT];
#pragma unroll
    for (int ii = 0; ii < IT; ++ii)
        axr_i[ii] = axr[(b * HEADS + h) * N + i0 + ii];

    // ---- Phase 1: scores ----
    float e[IT][NT];
    const float4* xlT4 = (const float4*)xlT + (size_t)(b * 32 + h * 8) * N;
    const float*  axlh = axl + (size_t)(b * HEADS + h) * N;
#pragma unroll
    for (int jt = 0; jt < NT; ++jt) {
        const int j = jt * 64 + lane;
        const float alj = axlh[j];
        float xlv[PER_HEAD];
#pragma unroll
        for (int q = 0; q < 8; ++q) {
            const float4 v = xlT4[q * N + j];
            xlv[q * 4 + 0] = v.x;
            xlv[q * 4 + 1] = v.y;
            xlv[q * 4 + 2] = v.z;
            xlv[q * 4 + 3] = v.w;
        }
#pragma unroll
        for (int ii = 0; ii < IT; ++ii) {
            float acc = 0.f;
#pragma unroll
            for (int c = 0; c < PER_HEAD; ++c) {
                const float s = xrv[ii][c] + xlv[c];
                acc = fmaf(att04[c], fabsf(s), acc);   // free VOP3 abs()
            }
            const float ev = fmaf(0.6f, axr_i[ii] + alj, acc);
            const unsigned long long m = maskT[(size_t)(b * N + i0 + ii) * NT + jt];
            e[ii][jt] = ((m >> lane) & 1ull) ? ev : -1e30f;
        }
    }

    // ---- Phase 2: softmax (register), unnormalized alpha -> LDS ----
    float inv[IT];
#pragma unroll
    for (int ii = 0; ii < IT; ++ii) {
        float m = e[ii][0];
#pragma unroll
        for (int t = 1; t < NT; ++t) m = fmaxf(m, e[ii][t]);
#pragma unroll
        for (int d = 1; d < 64; d <<= 1) m = fmaxf(m, __shfl_xor(m, d));
        float ssum = 0.f;
#pragma unroll
        for (int t = 0; t < NT; ++t) {
            const float a = __expf(e[ii][t] - m);
            a_s[ii][t * 64 + lane] = a;
            ssum += a;
        }
#pragma unroll
        for (int d = 1; d < 64; d <<= 1) ssum += __shfl_xor(ssum, d);
        inv[ii] = 1.f / ssum;
    }
    // same wave wrote a_s -> no barrier needed

    // ---- Phase 3: aggregation from xlT4 (same values xl held; L1-warm) ----
    const int cg = lane & 7;              // channel group (4 ch)
    const int jg = lane >> 3;             // 8 j's per iteration
    const float4* rowp = xlT4 + (size_t)cg * N;

    float ax[IT], ay[IT], az[IT], aw[IT];
#pragma unroll
    for (int ii = 0; ii < IT; ++ii) { ax[ii] = ay[ii] = az[ii] = aw[ii] = 0.f; }

#pragma unroll 8
    for (int jo = 0; jo < N / 8; ++jo) {
        const int j = jo * 8 + jg;
        const float4 xv = rowp[j];
#pragma unroll
        for (int ii = 0; ii < IT; ++ii) {
            const float av = a_s[ii][j];
            ax[ii] = fmaf(av, xv.x, ax[ii]);
            ay[ii] = fmaf(av, xv.y, ay[ii]);
            az[ii] = fmaf(av, xv.z, az[ii]);
            aw[ii] = fmaf(av, xv.w, aw[ii]);
        }
    }

#pragma unroll
    for (int ii = 0; ii < IT; ++ii) {
        float rx = ax[ii], ry = ay[ii], rz = az[ii], rw = aw[ii];
#pragma unroll
        for (int d = 8; d < 64; d <<= 1) {
            rx += __shfl_xor(rx, d);
            ry += __shfl_xor(ry, d);
            rz += __shfl_xor(rz, d);
            rw += __shfl_xor(rw, d);
        }
        if (jg == 0) {
            const float s = inv[ii];
            const int cb = h * PER_HEAD + cg * 4;
            const int ob = (b * N + i0 + ii) * OUT_DIM + cb;
            const float4 r = make_float4(rx * s + bias[cb + 0],
                                         ry * s + bias[cb + 1],
                                         rz * s + bias[cb + 2],
                                         rw * s + bias[cb + 3]);
            *(float4*)(out + ob) = r;
        }
    }
}

extern "C" void kernel_launch(void* const* d_in, const int* in_sizes, int n_in,
                              void* d_out, int out_size, void* d_ws, size_t ws_size,
                              hipStream_t stream) {
    const float* x    = (const float*)d_in[0];
    const int*   adj  = (const int*)d_in[1];
    const float* Wl   = (const float*)d_in[2];
    const float* bl   = (const float*)d_in[3];
    const float* Wr   = (const float*)d_in[4];
    const float* br   = (const float*)d_in[5];
    const float* att  = (const float*)d_in[6];
    const float* bias = (const float*)d_in[7];
    float* out = (float*)d_out;

    // ws layout byte-identical to green R9 (slot at +0 was xl, now unused).
    char* ws = (char*)d_ws;
    float* xr   = (float*)(ws + (1u << 20));            // 1 MB
    float* xlT  = (float*)(ws + (2u << 20));            // 1 MB
    unsigned long long* maskT =
        (unsigned long long*)(ws + (3u << 20));         // 128 KB
    float* axl  = (float*)(ws + (3u << 20) + (1u << 17));              // 32 KB
    float* axr  = (float*)(ws + (3u << 20) + (1u << 17) + (1u << 15)); // 32 KB

    gat_linear<<<dim3(B * N / LROWS), dim3(128), 0, stream>>>(
        x, Wl, bl, Wr, br, att, xr, xlT, axl, axr);
    gat_mask<<<dim3(N / 64, B), dim3(256), 0, stream>>>(adj, maskT);
    gat_attn<<<dim3(N / IT, HEADS, B), dim3(64), 0, stream>>>(
        xr, xlT, axl, axr, maskT, att, bias, out);
}

// Round 12
// 121.717 us; speedup vs baseline: 1.0570x; 1.0570x over previous
//
#include <hip/hip_runtime.h>
#include <hip/hip_bf16.h>
#include <math.h>

#define B 4
#define N 512
#define IN_DIM 128
#define OUT_DIM 128
#define HEADS 4
#define PER_HEAD 32
#define NT (N / 64)   // 8 j-tiles of 64
#define IT 2          // target nodes per block (attn)
#define LROWS 4       // rows per block (linear)
#define NP4 (N + 4)   // padded xlT row length in float4 units (8256 B stride
                      // breaks the 8 KB power-of-2 L1 set aliasing seen in R11)

// R12 = R11 + ONE delta: xlT rows padded +64 B (NP4). R11 evidence: attn
// 47 us, VALUBusy 26%, FETCH 5.75 MB -> latency-stalled; xlT4 rows at
// exactly 8 KB stride all map to one L1 set (bits [12:6]) -> 8-line
// conflict > associativity -> L1 thrash in phases 1 and 3.

// ---------------------------------------------------------------------------
// Kernel 1: xr = x@Wr+br; xl = x@Wl+bl stored ONLY transposed (ch-group-of-4,
// padded rows); axl/axr = att-dot rows for the factorized leaky score.
// ---------------------------------------------------------------------------
__global__ __launch_bounds__(128) void gat_linear(
    const float* __restrict__ x, const float* __restrict__ Wl,
    const float* __restrict__ bl, const float* __restrict__ Wr,
    const float* __restrict__ br, const float* __restrict__ att,
    float* __restrict__ xr, float* __restrict__ xlT,
    float* __restrict__ axl, float* __restrict__ axr) {
    const int r0  = blockIdx.x * LROWS;
    const int col = threadIdx.x;          // col = h*32 + c
    __shared__ float xs[LROWS][IN_DIM];
#pragma unroll
    for (int r = 0; r < LROWS; ++r)
        xs[r][col] = x[(r0 + r) * IN_DIM + col];
    __syncthreads();

    float accl[LROWS], accr[LROWS];
    {
        const float blv = bl[col];
        const float brv = br[col];
#pragma unroll
        for (int r = 0; r < LROWS; ++r) { accl[r] = blv; accr[r] = brv; }
    }
#pragma unroll 8
    for (int k = 0; k < IN_DIM; ++k) {
        const float wl = Wl[k * OUT_DIM + col];
        const float wr = Wr[k * OUT_DIM + col];
#pragma unroll
        for (int r = 0; r < LROWS; ++r) {
            accl[r] = fmaf(xs[r][k], wl, accl[r]);
            accr[r] = fmaf(xs[r][k], wr, accr[r]);
        }
    }
    const float attc = att[col];          // att[h*PER_HEAD + c] == att[col]
    const int h = col >> 5;
#pragma unroll
    for (int r = 0; r < LROWS; ++r) {
        const int row = r0 + r;
        const int b = row >> 9, n = row & (N - 1);
        xr[row * OUT_DIM + col] = accr[r];
        xlT[((b * 32 + (col >> 2)) * NP4 + n) * 4 + (col & 3)] = accl[r];
        // att-dot over the 32-lane channel group (lanes [0,31]/[32,63] of wave)
        float pl = attc * accl[r];
        float pr = attc * accr[r];
#pragma unroll
        for (int d = 1; d < 32; d <<= 1) {
            pl += __shfl_xor(pl, d);
            pr += __shfl_xor(pr, d);
        }
        if ((col & 31) == 0) {
            axl[(b * HEADS + h) * N + n] = pl;
            axr[(b * HEADS + h) * N + n] = pr;
        }
    }
}

// ---------------------------------------------------------------------------
// Kernel 2: adjacency bitmask, transposed, diagonal forced. lane <-> i
// (coalesced adj rows); each lane assembles its own u64 over j. (unchanged)
// ---------------------------------------------------------------------------
__global__ __launch_bounds__(256) void gat_mask(
    const int* __restrict__ adj, unsigned long long* __restrict__ maskT) {
    const int b    = blockIdx.y;
    const int i    = blockIdx.x * 64 + (threadIdx.x & 63);
    const int wave = threadIdx.x >> 6;
    for (int t = wave; t < NT; t += 4) {
        unsigned long long m = 0ull;
#pragma unroll 8
        for (int jj = 0; jj < 64; ++jj) {
            const int j = t * 64 + jj;
            const int v = adj[((size_t)b * N + j) * N + i];
            m |= (unsigned long long)(v != 0) << jj;
        }
        if ((i >> 6) == t) m |= 1ull << (i & 63);   // self-loop
        maskT[(size_t)(b * N + i) * NT + t] = m;
    }
}

// ---------------------------------------------------------------------------
// Kernel 3: fused scores + segment-softmax + aggregation. 1 wave per block.
// e_ij = 0.6(axr_i+axl_j) + sum_c 0.4*att_c*|xr_i+xl_j|; reads padded xlT4.
// ---------------------------------------------------------------------------
__global__ __launch_bounds__(64) void gat_attn(
    const float* __restrict__ xr, const float* __restrict__ xlT,
    const float* __restrict__ axl, const float* __restrict__ axr,
    const unsigned long long* __restrict__ maskT,
    const float* __restrict__ att, const float* __restrict__ bias,
    float* __restrict__ out) {
    const int lane = threadIdx.x;         // 0..63 (one wave)
    const int h    = blockIdx.y;          // head
    const int i0   = blockIdx.x * IT;
    const int b    = blockIdx.z;

    __shared__ float a_s[IT][N];          // 4 KB

    float att04[PER_HEAD];                // 0.4 * att
#pragma unroll
    for (int c = 0; c < PER_HEAD; ++c) att04[c] = 0.4f * att[h * PER_HEAD + c];
    float xrv[IT][PER_HEAD];
#pragma unroll
    for (int ii = 0; ii < IT; ++ii)
#pragma unroll
        for (int c = 0; c < PER_HEAD; ++c)
            xrv[ii][c] = xr[(b * N + i0 + ii) * OUT_DIM + h * PER_HEAD + c];
    float axr_i[IT];
#pragma unroll
    for (int ii = 0; ii < IT; ++ii)
        axr_i[ii] = axr[(b * HEADS + h) * N + i0 + ii];

    // ---- Phase 1: scores ----
    float e[IT][NT];
    const float4* xlT4 = (const float4*)xlT + (size_t)(b * 32 + h * 8) * NP4;
    const float*  axlh = axl + (size_t)(b * HEADS + h) * N;
#pragma unroll
    for (int jt = 0; jt < NT; ++jt) {
        const int j = jt * 64 + lane;
        const float alj = axlh[j];
        float xlv[PER_HEAD];
#pragma unroll
        for (int q = 0; q < 8; ++q) {
            const float4 v = xlT4[q * NP4 + j];
            xlv[q * 4 + 0] = v.x;
            xlv[q * 4 + 1] = v.y;
            xlv[q * 4 + 2] = v.z;
            xlv[q * 4 + 3] = v.w;
        }
#pragma unroll
        for (int ii = 0; ii < IT; ++ii) {
            float acc = 0.f;
#pragma unroll
            for (int c = 0; c < PER_HEAD; ++c) {
                const float s = xrv[ii][c] + xlv[c];
                acc = fmaf(att04[c], fabsf(s), acc);   // free VOP3 abs()
            }
            const float ev = fmaf(0.6f, axr_i[ii] + alj, acc);
            const unsigned long long m = maskT[(size_t)(b * N + i0 + ii) * NT + jt];
            e[ii][jt] = ((m >> lane) & 1ull) ? ev : -1e30f;
        }
    }

    // ---- Phase 2: softmax (register), unnormalized alpha -> LDS ----
    float inv[IT];
#pragma unroll
    for (int ii = 0; ii < IT; ++ii) {
        float m = e[ii][0];
#pragma unroll
        for (int t = 1; t < NT; ++t) m = fmaxf(m, e[ii][t]);
#pragma unroll
        for (int d = 1; d < 64; d <<= 1) m = fmaxf(m, __shfl_xor(m, d));
        float ssum = 0.f;
#pragma unroll
        for (int t = 0; t < NT; ++t) {
            const float a = __expf(e[ii][t] - m);
            a_s[ii][t * 64 + lane] = a;
            ssum += a;
        }
#pragma unroll
        for (int d = 1; d < 64; d <<= 1) ssum += __shfl_xor(ssum, d);
        inv[ii] = 1.f / ssum;
    }
    // same wave wrote a_s -> no barrier needed

    // ---- Phase 3: aggregation from padded xlT4 ----
    const int cg = lane & 7;              // channel group (4 ch)
    const int jg = lane >> 3;             // 8 j's per iteration
    const float4* rowp = xlT4 + (size_t)cg * NP4;

    float ax[IT], ay[IT], az[IT], aw[IT];
#pragma unroll
    for (int ii = 0; ii < IT; ++ii) { ax[ii] = ay[ii] = az[ii] = aw[ii] = 0.f; }

#pragma unroll 8
    for (int jo = 0; jo < N / 8; ++jo) {
        const int j = jo * 8 + jg;
        const float4 xv = rowp[j];
#pragma unroll
        for (int ii = 0; ii < IT; ++ii) {
            const float av = a_s[ii][j];
            ax[ii] = fmaf(av, xv.x, ax[ii]);
            ay[ii] = fmaf(av, xv.y, ay[ii]);
            az[ii] = fmaf(av, xv.z, az[ii]);
            aw[ii] = fmaf(av, xv.w, aw[ii]);
        }
    }

#pragma unroll
    for (int ii = 0; ii < IT; ++ii) {
        float rx = ax[ii], ry = ay[ii], rz = az[ii], rw = aw[ii];
#pragma unroll
        for (int d = 8; d < 64; d <<= 1) {
            rx += __shfl_xor(rx, d);
            ry += __shfl_xor(ry, d);
            rz += __shfl_xor(rz, d);
            rw += __shfl_xor(rw, d);
        }
        if (jg == 0) {
            const float s = inv[ii];
            const int cb = h * PER_HEAD + cg * 4;
            const int ob = (b * N + i0 + ii) * OUT_DIM + cb;
            const float4 r = make_float4(rx * s + bias[cb + 0],
                                         ry * s + bias[cb + 1],
                                         rz * s + bias[cb + 2],
                                         rw * s + bias[cb + 3]);
            *(float4*)(out + ob) = r;
        }
    }
}

extern "C" void kernel_launch(void* const* d_in, const int* in_sizes, int n_in,
                              void* d_out, int out_size, void* d_ws, size_t ws_size,
                              hipStream_t stream) {
    const float* x    = (const float*)d_in[0];
    const int*   adj  = (const int*)d_in[1];
    const float* Wl   = (const float*)d_in[2];
    const float* bl   = (const float*)d_in[3];
    const float* Wr   = (const float*)d_in[4];
    const float* br   = (const float*)d_in[5];
    const float* att  = (const float*)d_in[6];
    const float* bias = (const float*)d_in[7];
    float* out = (float*)d_out;

    char* ws = (char*)d_ws;
    float* xr   = (float*)(ws);                          // 1 MB
    float* xlT  = (float*)(ws + (1u << 20));             // 128*516*16 B ~1.06 MB
    unsigned long long* maskT =
        (unsigned long long*)(ws + 2359296u);            // 128 KB @ 2.25 MB
    float* axl  = (float*)(ws + 2490368u);               // 32 KB
    float* axr  = (float*)(ws + 2523136u);               // 32 KB

    gat_linear<<<dim3(B * N / LROWS), dim3(128), 0, stream>>>(
        x, Wl, bl, Wr, br, att, xr, xlT, axl, axr);
    gat_mask<<<dim3(N / 64, B), dim3(256), 0, stream>>>(adj, maskT);
    gat_attn<<<dim3(N / IT, HEADS, B), dim3(64), 0, stream>>>(
        xr, xlT, axl, axr, maskT, att, bias, out);
}

// Round 13
// 112.327 us; speedup vs baseline: 1.1454x; 1.0836x over previous
//
#include <hip/hip_runtime.h>
#include <hip/hip_bf16.h>
#include <math.h>

#define B 4
#define N 512
#define IN_DIM 128
#define OUT_DIM 128
#define HEADS 4
#define PER_HEAD 32
#define NT (N / 64)   // 8 j-tiles of 64
#define IT 2          // target nodes per block (attn)
#define LROWS 4       // rows per block (linear)
#define NP4 (N + 4)   // padded xlT row length in float4 units

// R13 = R12 + ONE delta: phase-3 lane map swapped to cg=lane>>3, jg=lane&7.
// R11/R12 post-mortem: old map (cg=lane&7) put adjacent lanes 8 KB apart ->
// 64 cache lines per wave load; new map: 8 consecutive lanes read 128 B
// contiguous within one row -> ~16-24 lines/wave (R9-level coalescing).
// Reduction over jg bits (d=1,2,4); a_s read becomes an LDS broadcast.

// ---------------------------------------------------------------------------
// Kernel 1: xr = x@Wr+br; xl = x@Wl+bl stored ONLY transposed (ch-group-of-4,
// padded rows); axl/axr = att-dot rows for the factorized leaky score.
// ---------------------------------------------------------------------------
__global__ __launch_bounds__(128) void gat_linear(
    const float* __restrict__ x, const float* __restrict__ Wl,
    const float* __restrict__ bl, const float* __restrict__ Wr,
    const float* __restrict__ br, const float* __restrict__ att,
    float* __restrict__ xr, float* __restrict__ xlT,
    float* __restrict__ axl, float* __restrict__ axr) {
    const int r0  = blockIdx.x * LROWS;
    const int col = threadIdx.x;          // col = h*32 + c
    __shared__ float xs[LROWS][IN_DIM];
#pragma unroll
    for (int r = 0; r < LROWS; ++r)
        xs[r][col] = x[(r0 + r) * IN_DIM + col];
    __syncthreads();

    float accl[LROWS], accr[LROWS];
    {
        const float blv = bl[col];
        const float brv = br[col];
#pragma unroll
        for (int r = 0; r < LROWS; ++r) { accl[r] = blv; accr[r] = brv; }
    }
#pragma unroll 8
    for (int k = 0; k < IN_DIM; ++k) {
        const float wl = Wl[k * OUT_DIM + col];
        const float wr = Wr[k * OUT_DIM + col];
#pragma unroll
        for (int r = 0; r < LROWS; ++r) {
            accl[r] = fmaf(xs[r][k], wl, accl[r]);
            accr[r] = fmaf(xs[r][k], wr, accr[r]);
        }
    }
    const float attc = att[col];          // att[h*PER_HEAD + c] == att[col]
    const int h = col >> 5;
#pragma unroll
    for (int r = 0; r < LROWS; ++r) {
        const int row = r0 + r;
        const int b = row >> 9, n = row & (N - 1);
        xr[row * OUT_DIM + col] = accr[r];
        xlT[((b * 32 + (col >> 2)) * NP4 + n) * 4 + (col & 3)] = accl[r];
        // att-dot over the 32-lane channel group (lanes [0,31]/[32,63] of wave)
        float pl = attc * accl[r];
        float pr = attc * accr[r];
#pragma unroll
        for (int d = 1; d < 32; d <<= 1) {
            pl += __shfl_xor(pl, d);
            pr += __shfl_xor(pr, d);
        }
        if ((col & 31) == 0) {
            axl[(b * HEADS + h) * N + n] = pl;
            axr[(b * HEADS + h) * N + n] = pr;
        }
    }
}

// ---------------------------------------------------------------------------
// Kernel 2: adjacency bitmask, transposed, diagonal forced. lane <-> i
// (coalesced adj rows); each lane assembles its own u64 over j. (unchanged)
// ---------------------------------------------------------------------------
__global__ __launch_bounds__(256) void gat_mask(
    const int* __restrict__ adj, unsigned long long* __restrict__ maskT) {
    const int b    = blockIdx.y;
    const int i    = blockIdx.x * 64 + (threadIdx.x & 63);
    const int wave = threadIdx.x >> 6;
    for (int t = wave; t < NT; t += 4) {
        unsigned long long m = 0ull;
#pragma unroll 8
        for (int jj = 0; jj < 64; ++jj) {
            const int j = t * 64 + jj;
            const int v = adj[((size_t)b * N + j) * N + i];
            m |= (unsigned long long)(v != 0) << jj;
        }
        if ((i >> 6) == t) m |= 1ull << (i & 63);   // self-loop
        maskT[(size_t)(b * N + i) * NT + t] = m;
    }
}

// ---------------------------------------------------------------------------
// Kernel 3: fused scores + segment-softmax + aggregation. 1 wave per block.
// e_ij = 0.6(axr_i+axl_j) + sum_c 0.4*att_c*|xr_i+xl_j|; reads padded xlT4.
// ---------------------------------------------------------------------------
__global__ __launch_bounds__(64) void gat_attn(
    const float* __restrict__ xr, const float* __restrict__ xlT,
    const float* __restrict__ axl, const float* __restrict__ axr,
    const unsigned long long* __restrict__ maskT,
    const float* __restrict__ att, const float* __restrict__ bias,
    float* __restrict__ out) {
    const int lane = threadIdx.x;         // 0..63 (one wave)
    const int h    = blockIdx.y;          // head
    const int i0   = blockIdx.x * IT;
    const int b    = blockIdx.z;

    __shared__ float a_s[IT][N];          // 4 KB

    float att04[PER_HEAD];                // 0.4 * att
#pragma unroll
    for (int c = 0; c < PER_HEAD; ++c) att04[c] = 0.4f * att[h * PER_HEAD + c];
    float xrv[IT][PER_HEAD];
#pragma unroll
    for (int ii = 0; ii < IT; ++ii)
#pragma unroll
        for (int c = 0; c < PER_HEAD; ++c)
            xrv[ii][c] = xr[(b * N + i0 + ii) * OUT_DIM + h * PER_HEAD + c];
    float axr_i[IT];
#pragma unroll
    for (int ii = 0; ii < IT; ++ii)
        axr_i[ii] = axr[(b * HEADS + h) * N + i0 + ii];

    // ---- Phase 1: scores (lane = j within tile; fully coalesced) ----
    float e[IT][NT];
    const float4* xlT4 = (const float4*)xlT + (size_t)(b * 32 + h * 8) * NP4;
    const float*  axlh = axl + (size_t)(b * HEADS + h) * N;
#pragma unroll
    for (int jt = 0; jt < NT; ++jt) {
        const int j = jt * 64 + lane;
        const float alj = axlh[j];
        float xlv[PER_HEAD];
#pragma unroll
        for (int q = 0; q < 8; ++q) {
            const float4 v = xlT4[q * NP4 + j];
            xlv[q * 4 + 0] = v.x;
            xlv[q * 4 + 1] = v.y;
            xlv[q * 4 + 2] = v.z;
            xlv[q * 4 + 3] = v.w;
        }
#pragma unroll
        for (int ii = 0; ii < IT; ++ii) {
            float acc = 0.f;
#pragma unroll
            for (int c = 0; c < PER_HEAD; ++c) {
                const float s = xrv[ii][c] + xlv[c];
                acc = fmaf(att04[c], fabsf(s), acc);   // free VOP3 abs()
            }
            const float ev = fmaf(0.6f, axr_i[ii] + alj, acc);
            const unsigned long long m = maskT[(size_t)(b * N + i0 + ii) * NT + jt];
            e[ii][jt] = ((m >> lane) & 1ull) ? ev : -1e30f;
        }
    }

    // ---- Phase 2: softmax (register), unnormalized alpha -> LDS ----
    float inv[IT];
#pragma unroll
    for (int ii = 0; ii < IT; ++ii) {
        float m = e[ii][0];
#pragma unroll
        for (int t = 1; t < NT; ++t) m = fmaxf(m, e[ii][t]);
#pragma unroll
        for (int d = 1; d < 64; d <<= 1) m = fmaxf(m, __shfl_xor(m, d));
        float ssum = 0.f;
#pragma unroll
        for (int t = 0; t < NT; ++t) {
            const float a = __expf(e[ii][t] - m);
            a_s[ii][t * 64 + lane] = a;
            ssum += a;
        }
#pragma unroll
        for (int d = 1; d < 64; d <<= 1) ssum += __shfl_xor(ssum, d);
        inv[ii] = 1.f / ssum;
    }
    // same wave wrote a_s -> no barrier needed

    // ---- Phase 3: aggregation; cg=lane>>3 (row), jg=lane&7 (j-in-row) ----
    const int cg = lane >> 3;             // channel group (4 ch) -> row
    const int jg = lane & 7;              // 8 consecutive j's -> 128 B contig
    const float4* rowp = xlT4 + (size_t)cg * NP4;

    float ax[IT], ay[IT], az[IT], aw[IT];
#pragma unroll
    for (int ii = 0; ii < IT; ++ii) { ax[ii] = ay[ii] = az[ii] = aw[ii] = 0.f; }

#pragma unroll 8
    for (int jo = 0; jo < N / 8; ++jo) {
        const int j = jo * 8 + jg;
        const float4 xv = rowp[j];
#pragma unroll
        for (int ii = 0; ii < IT; ++ii) {
            const float av = a_s[ii][j];   // 8-lane broadcast per address
            ax[ii] = fmaf(av, xv.x, ax[ii]);
            ay[ii] = fmaf(av, xv.y, ay[ii]);
            az[ii] = fmaf(av, xv.z, az[ii]);
            aw[ii] = fmaf(av, xv.w, aw[ii]);
        }
    }

#pragma unroll
    for (int ii = 0; ii < IT; ++ii) {
        float rx = ax[ii], ry = ay[ii], rz = az[ii], rw = aw[ii];
#pragma unroll
        for (int d = 1; d < 8; d <<= 1) {   // reduce over jg bits
            rx += __shfl_xor(rx, d);
            ry += __shfl_xor(ry, d);
            rz += __shfl_xor(rz, d);
            rw += __shfl_xor(rw, d);
        }
        if (jg == 0) {
            const float s = inv[ii];
            const int cb = h * PER_HEAD + cg * 4;
            const int ob = (b * N + i0 + ii) * OUT_DIM + cb;
            const float4 r = make_float4(rx * s + bias[cb + 0],
                                         ry * s + bias[cb + 1],
                                         rz * s + bias[cb + 2],
                                         rw * s + bias[cb + 3]);
            *(float4*)(out + ob) = r;
        }
    }
}

extern "C" void kernel_launch(void* const* d_in, const int* in_sizes, int n_in,
                              void* d_out, int out_size, void* d_ws, size_t ws_size,
                              hipStream_t stream) {
    const float* x    = (const float*)d_in[0];
    const int*   adj  = (const int*)d_in[1];
    const float* Wl   = (const float*)d_in[2];
    const float* bl   = (const float*)d_in[3];
    const float* Wr   = (const float*)d_in[4];
    const float* br   = (const float*)d_in[5];
    const float* att  = (const float*)d_in[6];
    const float* bias = (const float*)d_in[7];
    float* out = (float*)d_out;

    char* ws = (char*)d_ws;
    float* xr   = (float*)(ws);                          // 1 MB
    float* xlT  = (float*)(ws + (1u << 20));             // 128*516*16 B ~1.06 MB
    unsigned long long* maskT =
        (unsigned long long*)(ws + 2359296u);            // 128 KB @ 2.25 MB
    float* axl  = (float*)(ws + 2490368u);               // 32 KB
    float* axr  = (float*)(ws + 2523136u);               // 32 KB

    gat_linear<<<dim3(B * N / LROWS), dim3(128), 0, stream>>>(
        x, Wl, bl, Wr, br, att, xr, xlT, axl, axr);
    gat_mask<<<dim3(N / 64, B), dim3(256), 0, stream>>>(adj, maskT);
    gat_attn<<<dim3(N / IT, HEADS, B), dim3(64), 0, stream>>>(
        xr, xlT, axl, axr, maskT, att, bias, out);
}

// Round 14
// 111.333 us; speedup vs baseline: 1.1556x; 1.0089x over previous
//
#include <hip/hip_runtime.h>
#include <hip/hip_bf16.h>
#include <math.h>

#define B 4
#define N 512
#define IN_DIM 128
#define OUT_DIM 128
#define HEADS 4
#define PER_HEAD 32
#define NT (N / 64)   // 8 j-tiles of 64
#define IT 2          // target nodes per block (attn)
#define LROWS 4       // rows per block (linear)
#define NP4 (N + 4)   // padded xlT row length in float4 units

// R14 = R13 + ONE delta (attn only): __launch_bounds__(64,3) lifts the
// default 8-wave/SIMD 56-VGPR cap (R11 counter) that forced phase 1 into
// 8 serialized load->wait->compute rounds; masks (wave-uniform -> s_load)
// and alj hoisted off the per-tile critical path so the scheduler can
// software-pipeline the unrolled tile loop. linear/mask byte-identical R13.

// ---------------------------------------------------------------------------
// Kernel 1: xr = x@Wr+br; xl = x@Wl+bl stored ONLY transposed (ch-group-of-4,
// padded rows); axl/axr = att-dot rows for the factorized leaky score.
// ---------------------------------------------------------------------------
__global__ __launch_bounds__(128) void gat_linear(
    const float* __restrict__ x, const float* __restrict__ Wl,
    const float* __restrict__ bl, const float* __restrict__ Wr,
    const float* __restrict__ br, const float* __restrict__ att,
    float* __restrict__ xr, float* __restrict__ xlT,
    float* __restrict__ axl, float* __restrict__ axr) {
    const int r0  = blockIdx.x * LROWS;
    const int col = threadIdx.x;          // col = h*32 + c
    __shared__ float xs[LROWS][IN_DIM];
#pragma unroll
    for (int r = 0; r < LROWS; ++r)
        xs[r][col] = x[(r0 + r) * IN_DIM + col];
    __syncthreads();

    float accl[LROWS], accr[LROWS];
    {
        const float blv = bl[col];
        const float brv = br[col];
#pragma unroll
        for (int r = 0; r < LROWS; ++r) { accl[r] = blv; accr[r] = brv; }
    }
#pragma unroll 8
    for (int k = 0; k < IN_DIM; ++k) {
        const float wl = Wl[k * OUT_DIM + col];
        const float wr = Wr[k * OUT_DIM + col];
#pragma unroll
        for (int r = 0; r < LROWS; ++r) {
            accl[r] = fmaf(xs[r][k], wl, accl[r]);
            accr[r] = fmaf(xs[r][k], wr, accr[r]);
        }
    }
    const float attc = att[col];          // att[h*PER_HEAD + c] == att[col]
    const int h = col >> 5;
#pragma unroll
    for (int r = 0; r < LROWS; ++r) {
        const int row = r0 + r;
        const int b = row >> 9, n = row & (N - 1);
        xr[row * OUT_DIM + col] = accr[r];
        xlT[((b * 32 + (col >> 2)) * NP4 + n) * 4 + (col & 3)] = accl[r];
        // att-dot over the 32-lane channel group (lanes [0,31]/[32,63] of wave)
        float pl = attc * accl[r];
        float pr = attc * accr[r];
#pragma unroll
        for (int d = 1; d < 32; d <<= 1) {
            pl += __shfl_xor(pl, d);
            pr += __shfl_xor(pr, d);
        }
        if ((col & 31) == 0) {
            axl[(b * HEADS + h) * N + n] = pl;
            axr[(b * HEADS + h) * N + n] = pr;
        }
    }
}

// ---------------------------------------------------------------------------
// Kernel 2: adjacency bitmask, transposed, diagonal forced. lane <-> i
// (coalesced adj rows); each lane assembles its own u64 over j. (unchanged)
// ---------------------------------------------------------------------------
__global__ __launch_bounds__(256) void gat_mask(
    const int* __restrict__ adj, unsigned long long* __restrict__ maskT) {
    const int b    = blockIdx.y;
    const int i    = blockIdx.x * 64 + (threadIdx.x & 63);
    const int wave = threadIdx.x >> 6;
    for (int t = wave; t < NT; t += 4) {
        unsigned long long m = 0ull;
#pragma unroll 8
        for (int jj = 0; jj < 64; ++jj) {
            const int j = t * 64 + jj;
            const int v = adj[((size_t)b * N + j) * N + i];
            m |= (unsigned long long)(v != 0) << jj;
        }
        if ((i >> 6) == t) m |= 1ull << (i & 63);   // self-loop
        maskT[(size_t)(b * N + i) * NT + t] = m;
    }
}

// ---------------------------------------------------------------------------
// Kernel 3: fused scores + segment-softmax + aggregation. 1 wave per block.
// e_ij = 0.6(axr_i+axl_j) + sum_c 0.4*att_c*|xr_i+xl_j|; reads padded xlT4.
// ---------------------------------------------------------------------------
__global__ __launch_bounds__(64, 3) void gat_attn(
    const float* __restrict__ xr, const float* __restrict__ xlT,
    const float* __restrict__ axl, const float* __restrict__ axr,
    const unsigned long long* __restrict__ maskT,
    const float* __restrict__ att, const float* __restrict__ bias,
    float* __restrict__ out) {
    const int lane = threadIdx.x;         // 0..63 (one wave)
    const int h    = blockIdx.y;          // head
    const int i0   = blockIdx.x * IT;
    const int b    = blockIdx.z;

    __shared__ float a_s[IT][N];          // 4 KB

    float att04[PER_HEAD];                // 0.4 * att
#pragma unroll
    for (int c = 0; c < PER_HEAD; ++c) att04[c] = 0.4f * att[h * PER_HEAD + c];
    float xrv[IT][PER_HEAD];
#pragma unroll
    for (int ii = 0; ii < IT; ++ii)
#pragma unroll
        for (int c = 0; c < PER_HEAD; ++c)
            xrv[ii][c] = xr[(b * N + i0 + ii) * OUT_DIM + h * PER_HEAD + c];
    float axr_i[IT];
#pragma unroll
    for (int ii = 0; ii < IT; ++ii)
        axr_i[ii] = axr[(b * HEADS + h) * N + i0 + ii];

    // ---- hoisted off the tile critical path: masks (uniform -> s_load),
    //      per-lane axl values ----
    const float4* xlT4 = (const float4*)xlT + (size_t)(b * 32 + h * 8) * NP4;
    const float*  axlh = axl + (size_t)(b * HEADS + h) * N;
    unsigned long long mk[IT][NT];
#pragma unroll
    for (int ii = 0; ii < IT; ++ii)
#pragma unroll
        for (int jt = 0; jt < NT; ++jt)
            mk[ii][jt] = maskT[(size_t)(b * N + i0 + ii) * NT + jt];
    float alj[NT];
#pragma unroll
    for (int jt = 0; jt < NT; ++jt) alj[jt] = axlh[jt * 64 + lane];

    // ---- Phase 1: scores (lane = j within tile; fully coalesced) ----
    float e[IT][NT];
#pragma unroll
    for (int jt = 0; jt < NT; ++jt) {
        const int j = jt * 64 + lane;
        float xlv[PER_HEAD];
#pragma unroll
        for (int q = 0; q < 8; ++q) {
            const float4 v = xlT4[q * NP4 + j];
            xlv[q * 4 + 0] = v.x;
            xlv[q * 4 + 1] = v.y;
            xlv[q * 4 + 2] = v.z;
            xlv[q * 4 + 3] = v.w;
        }
#pragma unroll
        for (int ii = 0; ii < IT; ++ii) {
            float acc = 0.f;
#pragma unroll
            for (int c = 0; c < PER_HEAD; ++c) {
                const float s = xrv[ii][c] + xlv[c];
                acc = fmaf(att04[c], fabsf(s), acc);   // free VOP3 abs()
            }
            const float ev = fmaf(0.6f, axr_i[ii] + alj[jt], acc);
            e[ii][jt] = ((mk[ii][jt] >> lane) & 1ull) ? ev : -1e30f;
        }
    }

    // ---- Phase 2: softmax (register), unnormalized alpha -> LDS ----
    float inv[IT];
#pragma unroll
    for (int ii = 0; ii < IT; ++ii) {
        float m = e[ii][0];
#pragma unroll
        for (int t = 1; t < NT; ++t) m = fmaxf(m, e[ii][t]);
#pragma unroll
        for (int d = 1; d < 64; d <<= 1) m = fmaxf(m, __shfl_xor(m, d));
        float ssum = 0.f;
#pragma unroll
        for (int t = 0; t < NT; ++t) {
            const float a = __expf(e[ii][t] - m);
            a_s[ii][t * 64 + lane] = a;
            ssum += a;
        }
#pragma unroll
        for (int d = 1; d < 64; d <<= 1) ssum += __shfl_xor(ssum, d);
        inv[ii] = 1.f / ssum;
    }
    // same wave wrote a_s -> no barrier needed

    // ---- Phase 3: aggregation; cg=lane>>3 (row), jg=lane&7 (j-in-row) ----
    const int cg = lane >> 3;             // channel group (4 ch) -> row
    const int jg = lane & 7;              // 8 consecutive j's -> 128 B contig
    const float4* rowp = xlT4 + (size_t)cg * NP4;

    float ax[IT], ay[IT], az[IT], aw[IT];
#pragma unroll
    for (int ii = 0; ii < IT; ++ii) { ax[ii] = ay[ii] = az[ii] = aw[ii] = 0.f; }

#pragma unroll 8
    for (int jo = 0; jo < N / 8; ++jo) {
        const int j = jo * 8 + jg;
        const float4 xv = rowp[j];
#pragma unroll
        for (int ii = 0; ii < IT; ++ii) {
            const float av = a_s[ii][j];   // 8-lane broadcast per address
            ax[ii] = fmaf(av, xv.x, ax[ii]);
            ay[ii] = fmaf(av, xv.y, ay[ii]);
            az[ii] = fmaf(av, xv.z, az[ii]);
            aw[ii] = fmaf(av, xv.w, aw[ii]);
        }
    }

#pragma unroll
    for (int ii = 0; ii < IT; ++ii) {
        float rx = ax[ii], ry = ay[ii], rz = az[ii], rw = aw[ii];
#pragma unroll
        for (int d = 1; d < 8; d <<= 1) {   // reduce over jg bits
            rx += __shfl_xor(rx, d);
            ry += __shfl_xor(ry, d);
            rz += __shfl_xor(rz, d);
            rw += __shfl_xor(rw, d);
        }
        if (jg == 0) {
            const float s = inv[ii];
            const int cb = h * PER_HEAD + cg * 4;
            const int ob = (b * N + i0 + ii) * OUT_DIM + cb;
            const float4 r = make_float4(rx * s + bias[cb + 0],
                                         ry * s + bias[cb + 1],
                                         rz * s + bias[cb + 2],
                                         rw * s + bias[cb + 3]);
            *(float4*)(out + ob) = r;
        }
    }
}

extern "C" void kernel_launch(void* const* d_in, const int* in_sizes, int n_in,
                              void* d_out, int out_size, void* d_ws, size_t ws_size,
                              hipStream_t stream) {
    const float* x    = (const float*)d_in[0];
    const int*   adj  = (const int*)d_in[1];
    const float* Wl   = (const float*)d_in[2];
    const float* bl   = (const float*)d_in[3];
    const float* Wr   = (const float*)d_in[4];
    const float* br   = (const float*)d_in[5];
    const float* att  = (const float*)d_in[6];
    const float* bias = (const float*)d_in[7];
    float* out = (float*)d_out;

    char* ws = (char*)d_ws;
    float* xr   = (float*)(ws);                          // 1 MB
    float* xlT  = (float*)(ws + (1u << 20));             // 128*516*16 B ~1.06 MB
    unsigned long long* maskT =
        (unsigned long long*)(ws + 2359296u);            // 128 KB @ 2.25 MB
    float* axl  = (float*)(ws + 2490368u);               // 32 KB
    float* axr  = (float*)(ws + 2523136u);               // 32 KB

    gat_linear<<<dim3(B * N / LROWS), dim3(128), 0, stream>>>(
        x, Wl, bl, Wr, br, att, xr, xlT, axl, axr);
    gat_mask<<<dim3(N / 64, B), dim3(256), 0, stream>>>(adj, maskT);
    gat_attn<<<dim3(N / IT, HEADS, B), dim3(64), 0, stream>>>(
        xr, xlT, axl, axr, maskT, att, bias, out);
}